// Round 9
// baseline (186.232 us; speedup 1.0000x reference)
//
#include <hip/hip_runtime.h>
#include <hip/hip_fp16.h>

#define DIMN 192
#define SD (DIMN * DIMN)             // 36864
#define CS (DIMN * DIMN * DIMN)      // 7077888
#define WIN_F 729.0f
#define NBLK2 1536                   // k2 blocks (6144 waves)

typedef unsigned int uint32;

__device__ __forceinline__ float2 up32(uint32 u) {
    __half2 h = *(__half2*)&u;
    return __half22float2(h);
}
__device__ __forceinline__ uint32 pk32(float x, float y) {
    __half2 h = __floats2half2_rn(x, y);
    return *(uint32*)&h;
}

// ---------------------------------------------------------------------------
// K1: products + D-pass. Thread per (h,w), walks one 24-deep d-chunk (+8
// halo, 32 slices). Raw (iv,jv) 9-ring; 5 running window sums incremental.
// Stores interleaved: s0123[pt] = uint2{pk(s0,s1), pk(s2,s3)}, s4[pt] = half.
// grid = 8 chunks x 144 = 1152 blocks x 256 (18 waves/CU).
// ---------------------------------------------------------------------------
__global__ __launch_bounds__(256) void k1_d(const float* __restrict__ I,
                                            const float* __restrict__ J,
                                            uint2* __restrict__ s0123,
                                            __half* __restrict__ s4) {
    const int chunk = blockIdx.x / 144;
    const int hw = (blockIdx.x % 144) * 256 + threadIdx.x;
    const int d0 = chunk * 24;

    float ri[9], rj[9];
#pragma unroll
    for (int k = 0; k < 9; k++) { ri[k] = 0.f; rj[k] = 0.f; }
    float r0 = 0.f, r1 = 0.f, r2 = 0.f, r3 = 0.f, r4 = 0.f;

    for (int i = 0; i < 32; i++) {
        const int ds = d0 - 4 + i;               // block-uniform predicate
        float iv = 0.f, jv = 0.f;
        if ((unsigned)ds < DIMN) {
            iv = I[ds * SD + hw];
            jv = J[ds * SD + hw];
        }
        const float oi = ri[0], oj = rj[0];      // slice leaving the window
        r0 += iv - oi;
        r1 += jv - oj;
        r2 += iv * iv - oi * oi;
        r3 += jv * jv - oj * oj;
        r4 += iv * jv - oi * oj;
#pragma unroll
        for (int k = 0; k < 8; k++) { ri[k] = ri[k + 1]; rj[k] = rj[k + 1]; }
        ri[8] = iv;
        rj[8] = jv;

        if (i >= 8) {
            const int o = (d0 + i - 8) * SD + hw;
            s0123[o] = make_uint2(pk32(r0, r1), pk32(r2, r3));
            s4[o] = __float2half_rn(r4);
        }
    }
}

// ---------------------------------------------------------------------------
// K2: H-pass + W-pass + cc + full reduce, pair-packed.
// Lane l owns the w-pair (we, we+1), we = -4 + wseg*72 + 2l.
// 16 h-bands of 12 output rows (20-iter walk) -> 6144 waves = 24/CU for
// latency hiding (round-8 was 12/CU, grid-limited). H-window: running sums
// with departing-row re-read (L2-resident). W-pass: pack channel pair to
// half2, 4 shfl -> 9-tap sums for both outputs.
// Final reduce folded in: block partial -> f64 atomicAdd; last block (atomic
// counter) converts to -(mean) and writes d_out. Saves one launch.
// grid = 1536 blocks x 256 (192 d x 16 bands x 2 wsegs).
// ---------------------------------------------------------------------------
__global__ __launch_bounds__(256) void k2_hwcc(const uint2* __restrict__ s0123,
                                               const __half* __restrict__ s4,
                                               double* __restrict__ accum,
                                               uint32* __restrict__ counter,
                                               float* __restrict__ out) {
    const int tid = threadIdx.x;
    const int l = tid & 63;
    const int wg = blockIdx.x * 4 + (tid >> 6);     // 0..6143
    const int wseg = wg & 1;
    const int band = (wg >> 1) & 15;
    const int d = wg >> 5;                          // 0..191
    const int h0 = band * 12;
    const int we = -4 + wseg * 72 + 2 * l;
    const bool pok = ((unsigned)we < DIMN);         // pair fully in-volume
    const int lo = wseg * 96;
    const bool f = pok && (we >= lo) && (we < lo + 96);  // pair ownership
    const int cb = d * SD + we;

    float re0 = 0.f, re1 = 0.f, re2 = 0.f, re3 = 0.f, re4 = 0.f;
    float ro0 = 0.f, ro1 = 0.f, ro2 = 0.f, ro3 = 0.f, ro4 = 0.f;
    double acc = 0.0;

    for (int i = 0; i < 20; ++i) {
        const int hh = h0 - 4 + i;
        uint4 qa = make_uint4(0u, 0u, 0u, 0u);
        uint32 qa4 = 0u;
        if (pok && (unsigned)hh < DIMN) {
            const int o = cb + hh * DIMN;
            qa = *(const uint4*)(s0123 + o);
            qa4 = *(const uint32*)(s4 + o);
        }
        uint4 qs = make_uint4(0u, 0u, 0u, 0u);
        uint32 qs4 = 0u;
        const int hd = hh - 9;                      // row leaving the window
        if (i >= 9 && pok && (unsigned)hd < DIMN) {
            const int o = cb + hd * DIMN;
            qs = *(const uint4*)(s0123 + o);
            qs4 = *(const uint32*)(s4 + o);
        }
        float2 t;
        t = up32(qa.x); re0 += t.x; re1 += t.y;
        t = up32(qs.x); re0 -= t.x; re1 -= t.y;
        t = up32(qa.y); re2 += t.x; re3 += t.y;
        t = up32(qs.y); re2 -= t.x; re3 -= t.y;
        t = up32(qa.z); ro0 += t.x; ro1 += t.y;
        t = up32(qs.z); ro0 -= t.x; ro1 -= t.y;
        t = up32(qa.w); ro2 += t.x; ro3 += t.y;
        t = up32(qs.w); ro2 -= t.x; ro3 -= t.y;
        t = up32(qa4);  re4 += t.x; ro4 += t.y;
        t = up32(qs4);  re4 -= t.x; ro4 -= t.y;

        if (i >= 8) {
            float Se[5], So[5];
#define WTAP(c, rE, rO)                                                       \
            {                                                                 \
                const uint32 tc = pk32(rE, rO);                               \
                const float2 m2 = up32((uint32)__shfl((int)tc, l - 2, 64));   \
                const float2 m1 = up32((uint32)__shfl((int)tc, l - 1, 64));   \
                const float2 p1 = up32((uint32)__shfl((int)tc, l + 1, 64));   \
                const float2 p2 = up32((uint32)__shfl((int)tc, l + 2, 64));   \
                const float M = m1.x + m1.y + rE + rO + p1.x + p1.y;          \
                Se[c] = M + m2.x + m2.y + p2.x;                               \
                So[c] = M + m2.y + p2.x + p2.y;                               \
            }
            WTAP(0, re0, ro0)
            WTAP(1, re1, ro1)
            WTAP(2, re2, ro2)
            WTAP(3, re3, ro3)
            WTAP(4, re4, ro4)
#undef WTAP
            if (f) {
                {
                    const float u_I = Se[0] / WIN_F;
                    const float u_J = Se[1] / WIN_F;
                    const float cross = Se[4] - u_J * Se[0] - u_I * Se[1] + u_I * u_J * WIN_F;
                    const float I_var = Se[2] - 2.0f * u_I * Se[0] + u_I * u_I * WIN_F;
                    const float J_var = Se[3] - 2.0f * u_J * Se[1] + u_J * u_J * WIN_F;
                    acc += (double)(cross * cross / (I_var * J_var + 1e-5f));
                }
                {
                    const float u_I = So[0] / WIN_F;
                    const float u_J = So[1] / WIN_F;
                    const float cross = So[4] - u_J * So[0] - u_I * So[1] + u_I * u_J * WIN_F;
                    const float I_var = So[2] - 2.0f * u_I * So[0] + u_I * u_I * WIN_F;
                    const float J_var = So[3] - 2.0f * u_J * So[1] + u_J * u_J * WIN_F;
                    acc += (double)(cross * cross / (I_var * J_var + 1e-5f));
                }
            }
        }
    }

    __shared__ double wred[4];
#pragma unroll
    for (int off = 32; off > 0; off >>= 1) acc += __shfl_down(acc, off, 64);
    if ((tid & 63) == 0) wred[tid >> 6] = acc;
    __syncthreads();
    if (tid == 0) {
        const double bsum = wred[0] + wred[1] + wred[2] + wred[3];
        atomicAdd(accum, bsum);
        __threadfence();
        const uint32 old = atomicAdd(counter, 1u);
        if (old == NBLK2 - 1) {                     // last block finishes
            __threadfence();
            const double total = atomicAdd(accum, 0.0);
            out[0] = -(float)(total / (double)CS);
        }
    }
}

extern "C" void kernel_launch(void* const* d_in, const int* in_sizes, int n_in,
                              void* d_out, int out_size, void* d_ws, size_t ws_size,
                              hipStream_t stream) {
    const float* I = (const float*)d_in[0];   // y_true
    const float* J = (const float*)d_in[1];   // y_pred
    char* ws = (char*)d_ws;
    uint2*  s0123 = (uint2*)ws;                             // CS * 8 B
    __half* s4    = (__half*)(ws + (size_t)CS * 8);         // CS * 2 B
    double* accum = (double*)(ws + (size_t)CS * 10);        // 8 B
    uint32* counter = (uint32*)(ws + (size_t)CS * 10 + 8);  // 4 B
    float* out = (float*)d_out;

    hipMemsetAsync(ws + (size_t)CS * 10, 0, 16, stream);    // zero accum+counter
    hipLaunchKernelGGL(k1_d, dim3(1152), dim3(256), 0, stream, I, J, s0123, s4);
    hipLaunchKernelGGL(k2_hwcc, dim3(NBLK2), dim3(256), 0, stream,
                       (const uint2*)s0123, (const __half*)s4, accum, counter, out);
}

// Round 10
// 173.249 us; speedup vs baseline: 1.0749x; 1.0749x over previous
//
#include <hip/hip_runtime.h>
#include <hip/hip_fp16.h>

#define DIMN 192
#define SD (DIMN * DIMN)             // 36864
#define CS (DIMN * DIMN * DIMN)      // 7077888
#define WIN_F 729.0f
#define NBLK2 768                    // k2 blocks (3072 waves)

typedef unsigned int uint32;

__device__ __forceinline__ float2 up32(uint32 u) {
    __half2 h = *(__half2*)&u;
    return __half22float2(h);
}
__device__ __forceinline__ uint32 pk32(float x, float y) {
    __half2 h = __floats2half2_rn(x, y);
    return *(uint32*)&h;
}

// ---------------------------------------------------------------------------
// K1: products + D-pass. Thread per (h,w), walks one 24-deep d-chunk (+8
// halo, 32 slices). Raw (iv,jv) 9-ring; 5 running window sums incremental.
// Stores interleaved: s0123[pt] = uint2{pk(s0,s1), pk(s2,s3)}, s4[pt] = half.
// grid = 8 chunks x 144 = 1152 blocks x 256 (18 waves/CU).
// Chunk-halo partner blocks are 144 apart; 144 % 8 == 0 -> same XCD already.
// ---------------------------------------------------------------------------
__global__ __launch_bounds__(256) void k1_d(const float* __restrict__ I,
                                            const float* __restrict__ J,
                                            uint2* __restrict__ s0123,
                                            __half* __restrict__ s4) {
    const int chunk = blockIdx.x / 144;
    const int hw = (blockIdx.x % 144) * 256 + threadIdx.x;
    const int d0 = chunk * 24;

    float ri[9], rj[9];
#pragma unroll
    for (int k = 0; k < 9; k++) { ri[k] = 0.f; rj[k] = 0.f; }
    float r0 = 0.f, r1 = 0.f, r2 = 0.f, r3 = 0.f, r4 = 0.f;

    for (int i = 0; i < 32; i++) {
        const int ds = d0 - 4 + i;               // block-uniform predicate
        float iv = 0.f, jv = 0.f;
        if ((unsigned)ds < DIMN) {
            iv = I[ds * SD + hw];
            jv = J[ds * SD + hw];
        }
        const float oi = ri[0], oj = rj[0];      // slice leaving the window
        r0 += iv - oi;
        r1 += jv - oj;
        r2 += iv * iv - oi * oi;
        r3 += jv * jv - oj * oj;
        r4 += iv * jv - oi * oj;
#pragma unroll
        for (int k = 0; k < 8; k++) { ri[k] = ri[k + 1]; rj[k] = rj[k + 1]; }
        ri[8] = iv;
        rj[8] = jv;

        if (i >= 8) {
            const int o = (d0 + i - 8) * SD + hw;
            s0123[o] = make_uint2(pk32(r0, r1), pk32(r2, r3));
            s4[o] = __float2half_rn(r4);
        }
    }
}

// ---------------------------------------------------------------------------
// K2: H-pass + W-pass + cc + full reduce, pair-packed. Round-8 geometry
// (measured best: 8 bands x 24 output rows, 32-iter walk, 3072 waves) plus
// XCD-partitioned block swizzle: logical = (bid&7)*96 + bid>>3. With 8 XCDs
// round-robin on hw blockIdx, XCD k owns d in [24k, 24k+24) exclusively ->
// each d-slice's channel data lives in exactly ONE per-XCD L2 (round 8/9
// duplicated it across 4/8 XCDs; r9's 83us vs r8's 50us tracked that dup).
// Lane l owns w-pair (we,we+1), we = -4 + wseg*72 + 2l; H-window via
// departing-row re-read (L2-hot); W-pass via 4 shfl per channel on half2
// packs. Block partial -> f64 atomicAdd; last block writes -(mean) to d_out.
// ---------------------------------------------------------------------------
__global__ __launch_bounds__(256) void k2_hwcc(const uint2* __restrict__ s0123,
                                               const __half* __restrict__ s4,
                                               double* __restrict__ accum,
                                               uint32* __restrict__ counter,
                                               float* __restrict__ out) {
    const int tid = threadIdx.x;
    const int l = tid & 63;
    const int bid = blockIdx.x;
    const int logical = (bid & 7) * 96 + (bid >> 3);   // XCD partition
    const int wg = logical * 4 + (tid >> 6);           // 0..3071
    const int wseg = wg & 1;
    const int band = (wg >> 1) & 7;
    const int d = wg >> 4;                             // 0..191
    const int h0 = band * 24;
    const int we = -4 + wseg * 72 + 2 * l;
    const bool pok = ((unsigned)we < DIMN);            // pair fully in-volume
    const int lo = wseg * 96;
    const bool f = pok && (we >= lo) && (we < lo + 96);  // pair ownership
    const int cb = d * SD + we;

    float re0 = 0.f, re1 = 0.f, re2 = 0.f, re3 = 0.f, re4 = 0.f;
    float ro0 = 0.f, ro1 = 0.f, ro2 = 0.f, ro3 = 0.f, ro4 = 0.f;
    double acc = 0.0;

    for (int i = 0; i < 32; ++i) {
        const int hh = h0 - 4 + i;
        uint4 qa = make_uint4(0u, 0u, 0u, 0u);
        uint32 qa4 = 0u;
        if (pok && (unsigned)hh < DIMN) {
            const int o = cb + hh * DIMN;
            qa = *(const uint4*)(s0123 + o);
            qa4 = *(const uint32*)(s4 + o);
        }
        uint4 qs = make_uint4(0u, 0u, 0u, 0u);
        uint32 qs4 = 0u;
        const int hd = hh - 9;                      // row leaving the window
        if (i >= 9 && pok && (unsigned)hd < DIMN) {
            const int o = cb + hd * DIMN;
            qs = *(const uint4*)(s0123 + o);
            qs4 = *(const uint32*)(s4 + o);
        }
        float2 t;
        t = up32(qa.x); re0 += t.x; re1 += t.y;
        t = up32(qs.x); re0 -= t.x; re1 -= t.y;
        t = up32(qa.y); re2 += t.x; re3 += t.y;
        t = up32(qs.y); re2 -= t.x; re3 -= t.y;
        t = up32(qa.z); ro0 += t.x; ro1 += t.y;
        t = up32(qs.z); ro0 -= t.x; ro1 -= t.y;
        t = up32(qa.w); ro2 += t.x; ro3 += t.y;
        t = up32(qs.w); ro2 -= t.x; ro3 -= t.y;
        t = up32(qa4);  re4 += t.x; ro4 += t.y;
        t = up32(qs4);  re4 -= t.x; ro4 -= t.y;

        if (i >= 8) {
            float Se[5], So[5];
#define WTAP(c, rE, rO)                                                       \
            {                                                                 \
                const uint32 tc = pk32(rE, rO);                               \
                const float2 m2 = up32((uint32)__shfl((int)tc, l - 2, 64));   \
                const float2 m1 = up32((uint32)__shfl((int)tc, l - 1, 64));   \
                const float2 p1 = up32((uint32)__shfl((int)tc, l + 1, 64));   \
                const float2 p2 = up32((uint32)__shfl((int)tc, l + 2, 64));   \
                const float M = m1.x + m1.y + rE + rO + p1.x + p1.y;          \
                Se[c] = M + m2.x + m2.y + p2.x;                               \
                So[c] = M + m2.y + p2.x + p2.y;                               \
            }
            WTAP(0, re0, ro0)
            WTAP(1, re1, ro1)
            WTAP(2, re2, ro2)
            WTAP(3, re3, ro3)
            WTAP(4, re4, ro4)
#undef WTAP
            if (f) {
                {
                    const float u_I = Se[0] / WIN_F;
                    const float u_J = Se[1] / WIN_F;
                    const float cross = Se[4] - u_J * Se[0] - u_I * Se[1] + u_I * u_J * WIN_F;
                    const float I_var = Se[2] - 2.0f * u_I * Se[0] + u_I * u_I * WIN_F;
                    const float J_var = Se[3] - 2.0f * u_J * Se[1] + u_J * u_J * WIN_F;
                    acc += (double)(cross * cross / (I_var * J_var + 1e-5f));
                }
                {
                    const float u_I = So[0] / WIN_F;
                    const float u_J = So[1] / WIN_F;
                    const float cross = So[4] - u_J * So[0] - u_I * So[1] + u_I * u_J * WIN_F;
                    const float I_var = So[2] - 2.0f * u_I * So[0] + u_I * u_I * WIN_F;
                    const float J_var = So[3] - 2.0f * u_J * So[1] + u_J * u_J * WIN_F;
                    acc += (double)(cross * cross / (I_var * J_var + 1e-5f));
                }
            }
        }
    }

    __shared__ double wred[4];
#pragma unroll
    for (int off = 32; off > 0; off >>= 1) acc += __shfl_down(acc, off, 64);
    if ((tid & 63) == 0) wred[tid >> 6] = acc;
    __syncthreads();
    if (tid == 0) {
        const double bsum = wred[0] + wred[1] + wred[2] + wred[3];
        atomicAdd(accum, bsum);
        __threadfence();
        const uint32 old = atomicAdd(counter, 1u);
        if (old == NBLK2 - 1) {                     // last block finishes
            __threadfence();
            const double total = atomicAdd(accum, 0.0);
            out[0] = -(float)(total / (double)CS);
        }
    }
}

extern "C" void kernel_launch(void* const* d_in, const int* in_sizes, int n_in,
                              void* d_out, int out_size, void* d_ws, size_t ws_size,
                              hipStream_t stream) {
    const float* I = (const float*)d_in[0];   // y_true
    const float* J = (const float*)d_in[1];   // y_pred
    char* ws = (char*)d_ws;
    uint2*  s0123 = (uint2*)ws;                             // CS * 8 B
    __half* s4    = (__half*)(ws + (size_t)CS * 8);         // CS * 2 B
    double* accum = (double*)(ws + (size_t)CS * 10);        // 8 B
    uint32* counter = (uint32*)(ws + (size_t)CS * 10 + 8);  // 4 B
    float* out = (float*)d_out;

    hipMemsetAsync(ws + (size_t)CS * 10, 0, 16, stream);    // zero accum+counter
    hipLaunchKernelGGL(k1_d, dim3(1152), dim3(256), 0, stream, I, J, s0123, s4);
    hipLaunchKernelGGL(k2_hwcc, dim3(NBLK2), dim3(256), 0, stream,
                       (const uint2*)s0123, (const __half*)s4, accum, counter, out);
}